// Round 6
// baseline (457.997 us; speedup 1.0000x reference)
//
#include <hip/hip_runtime.h>
#include <cmath>

// Decoder_spirals R5: R4 (all-gload bf16 MFMA pipeline) with the U0 stride bug fixed:
// ups_mfma now takes separate A/B row strides (WpA, WpB). R4 read x1T (stride 3072)
// with Ub0's stride 2976 -> garbage B operand on the U0 upsample (absmax 0.116).
// Swizzle: slot s of row r holds global chunk (s - (r>>1)) & 3 (add-perm, bank-balanced);
// gload dest linear (HW lane*16B), source pre-swizzled, frag reads swizzled.

#define NB 16

typedef __attribute__((ext_vector_type(8))) short bf16x8;
typedef __attribute__((ext_vector_type(4))) float f32x4;

__device__ __forceinline__ unsigned short f2bf(float x) {
    union { float f; unsigned u; } v; v.f = x;
    unsigned r = v.u + 0x7FFFu + ((v.u >> 16) & 1u);
    return (unsigned short)(r >> 16);
}
__device__ __forceinline__ float bff(unsigned short h) {
    union { unsigned u; float f; } c; c.u = ((unsigned)h) << 16; return c.f;
}
__device__ __forceinline__ void gload16(const void* src, void* dst) {
    __builtin_amdgcn_global_load_lds(
        (const __attribute__((address_space(1))) unsigned int*)src,
        (__attribute__((address_space(3))) unsigned int*)dst, 16, 0, 0);
}

// ---------------- converters ----------------
__global__ __launch_bounds__(256) void cvt_ub(const float* __restrict__ src,
                                              unsigned short* __restrict__ dst,
                                              int V, int W, int Wp) {
    int k = blockIdx.x * 256 + threadIdx.x;
    int row = blockIdx.y;
    if (k >= Wp) return;
    float v = (row < V && k < W) ? src[(size_t)row * W + k] : 0.f;
    dst[(size_t)row * Wp + k] = f2bf(v);
}
__global__ __launch_bounds__(256) void cvt_wT(const float* __restrict__ w,
                                              unsigned short* __restrict__ wT,
                                              int K, int N, int total) {
    int id = blockIdx.x * 256 + threadIdx.x;
    if (id >= total) return;
    int n = id / K, k = id - n * K;
    wT[id] = f2bf(w[(size_t)k * N + n]);
}
__global__ __launch_bounds__(256) void cvt_sT(const int* __restrict__ S,
                                              int* __restrict__ ST,
                                              int V, int K, int total) {
    int id = blockIdx.x * 256 + threadIdx.x;
    if (id >= total) return;
    int k = id / V, v = id - k * V;
    ST[id] = S[(size_t)v * K + k];
}
__global__ __launch_bounds__(256) void zero16(int4* __restrict__ p, int n16) {
    int id = blockIdx.x * 256 + threadIdx.x;
    if (id < n16) p[id] = make_int4(0, 0, 0, 0);
}

// ---------------- FC: z(16,128)@Wfc(128,23680)+bfc -> x3T[b*128+f][192] bf16 ----------------
__global__ __launch_bounds__(256) void fc_kernel(const float* __restrict__ z,
                                                 const float* __restrict__ Wfc,
                                                 const float* __restrict__ bfc,
                                                 unsigned short* __restrict__ x3T) {
    const int N = 185 * 128;
    __shared__ float zs[NB * 128];
    int t = threadIdx.x;
    for (int i = t; i < NB * 128; i += 256) zs[i] = z[i];
    __syncthreads();
    int n = blockIdx.x * 256 + t;
    if (n >= N) return;
    float acc[NB];
#pragma unroll
    for (int b = 0; b < NB; ++b) acc[b] = 0.f;
    for (int k = 0; k < 128; ++k) {
        float w = Wfc[k * N + n];
#pragma unroll
        for (int b = 0; b < NB; ++b) acc[b] = fmaf(zs[b * 128 + k], w, acc[b]);
    }
    float bv = bfc[n];
    int f = n & 127, v = n >> 7;
#pragma unroll
    for (int b = 0; b < NB; ++b)
        x3T[(size_t)(b * 128 + f) * 192 + v] = f2bf(acc[b] + bv);
}

// ------------- Upsample: out[b,v,f] = sum_w U[v,w]*x[b,w,f] -------------
// A = Ub bf16 [.. ][WpA]; B = xT bf16 [(b,f)][WpB]; both staged via global_load_lds.
// 128x128 tile, BK=32, dbuf, 4 waves of 64x64. out = bf16 [b][VP][F].
template<int FSH, int VP>
__global__ __launch_bounds__(256) void ups_mfma(
    const unsigned short* __restrict__ Ub, const unsigned short* __restrict__ xT,
    unsigned short* __restrict__ out,
    int WpA, int WpB, int nsteps, int gxsh, int q) {
    const int F = 1 << FSH;
    __shared__ __align__(16) unsigned short As[2][128 * 32];
    __shared__ __align__(16) unsigned short Bs[2][128 * 32];
    const int t = threadIdx.x;
    const int wv = t >> 6, lane = t & 63;
    const int lr = lane & 15;

    // XCD-chunked bijective swizzle (nwg % 8 == 0)
    const int flat = blockIdx.x;
    const int wg = (flat & 7) * q + (flat >> 3);
    const int m0 = (wg >> gxsh) * 128;
    const int n0 = (wg & ((1 << gxsh) - 1)) * 128;

    // staging: unit ii = wv*2+i; HW writes lane's 16B at dest+lane*16
    //   -> row ii*16 + (lane>>2), slot lane&3; source chunk = (slot-(row>>1))&3
    const int srow = lane >> 2;
    const int schunk = (((lane & 3) - ((lane >> 3) & 3)) & 3) * 8;
    const unsigned short* asrc[2];
    const unsigned short* bsrc[2];
#pragma unroll
    for (int i = 0; i < 2; ++i) {
        const int ii = wv * 2 + i;
        asrc[i] = Ub + (size_t)(m0 + ii * 16 + srow) * WpA + schunk;
        bsrc[i] = xT + (size_t)(n0 + ii * 16 + srow) * WpB + schunk;
    }
    // frag reads: chunk = lane>>4 lives at slot (chunk + (lr>>1)) & 3
    const int fslot = (((lane >> 4) + (lr >> 1)) & 3) * 8;
    const int wrow = (wv >> 1) * 64;
    const int wcol = (wv & 1) * 64;

    f32x4 acc[4][4];
#pragma unroll
    for (int i = 0; i < 4; ++i)
#pragma unroll
        for (int j = 0; j < 4; ++j) acc[i][j] = {0.f, 0.f, 0.f, 0.f};

    // prologue: stage step 0 into buf 0
#pragma unroll
    for (int i = 0; i < 2; ++i) {
        const int ii = wv * 2 + i;
        gload16(asrc[i], &As[0][ii * 512]);
        gload16(bsrc[i], &Bs[0][ii * 512]);
    }
    __syncthreads();

    for (int ts = 0; ts < nsteps; ++ts) {
        const int cur = ts & 1, nbuf = cur ^ 1, tn = ts + 1;
        if (tn < nsteps) {
            const int k0 = tn * 32;
#pragma unroll
            for (int i = 0; i < 2; ++i) {
                const int ii = wv * 2 + i;
                gload16(asrc[i] + k0, &As[nbuf][ii * 512]);
                gload16(bsrc[i] + k0, &Bs[nbuf][ii * 512]);
            }
        }
        bf16x8 af[4], bg[4];
#pragma unroll
        for (int mt = 0; mt < 4; ++mt)
            af[mt] = *(const bf16x8*)&As[cur][(wrow + mt * 16 + lr) * 32 + fslot];
#pragma unroll
        for (int nt = 0; nt < 4; ++nt)
            bg[nt] = *(const bf16x8*)&Bs[cur][(wcol + nt * 16 + lr) * 32 + fslot];
#pragma unroll
        for (int mt = 0; mt < 4; ++mt)
#pragma unroll
            for (int nt = 0; nt < 4; ++nt)
                acc[mt][nt] = __builtin_amdgcn_mfma_f32_16x16x32_bf16(
                    af[mt], bg[nt], acc[mt][nt], 0, 0, 0);
        __syncthreads();
    }

    // epilogue: C row=(lane>>4)*4+j (m), col=lane&15 (n); write bf16 [b][VP][F]
#pragma unroll
    for (int mt = 0; mt < 4; ++mt) {
        const int vb = m0 + wrow + mt * 16 + (lane >> 4) * 4;
#pragma unroll
        for (int nt = 0; nt < 4; ++nt) {
            const int col = n0 + wcol + nt * 16 + lr;
            const int b = col >> FSH, f = col & (F - 1);
            unsigned short* op = out + (size_t)b * VP * F + f;
#pragma unroll
            for (int j = 0; j < 4; ++j)
                op[(size_t)(vb + j) * F] = f2bf(acc[mt][nt][j]);
        }
    }
}

// ------- SpiralConv: gathered-A bf16 GEMM + bias + ELU + zero dummy, transposed out -------
// 1 wave, 64x64 tile, BK=32, dbuf, Fin=128. out: xT[(b*Fout+n)][VP] bf16.
template<int VP>
__global__ __launch_bounds__(64) void conv_mfma(
    const unsigned short* __restrict__ xu, const int* __restrict__ ST,
    const unsigned short* __restrict__ WT, const float* __restrict__ bias,
    unsigned short* __restrict__ outT,
    int VT, int Ksp, int Kdim, int nsteps, int Fout) {
    __shared__ __align__(16) unsigned short As[2][64 * 32];
    __shared__ __align__(16) unsigned short Bs[2][64 * 32];
    const int lane = threadIdx.x;
    const int lr = lane & 15;
    const int m0 = blockIdx.x * 64;
    const int n0 = blockIdx.y * 64;
    const int b = m0 / VP;
    const int v0 = m0 - b * VP;
    const unsigned short* xb = xu + (((size_t)b * VP) << 7);

    const int vg = (v0 + lane < VT) ? (v0 + lane) : (VT - 1);
    const int schunk = (((lane & 3) - ((lane >> 3) & 3)) & 3) * 8;
    const int fslot = (((lane >> 4) + (lr >> 1)) & 3) * 8;
    int sw[4];
#pragma unroll
    for (int qq = 0; qq < 4; ++qq)
        sw[qq] = lane * 32 + (((qq + ((lane >> 1) & 3)) & 3) * 8);

    int s_c = 0;
    int idx_c = ST[vg];
    int idx_n = ST[(size_t)VT + vg];

    f32x4 acc[4][4];
#pragma unroll
    for (int i = 0; i < 4; ++i)
#pragma unroll
        for (int j = 0; j < 4; ++j) acc[i][j] = {0.f, 0.f, 0.f, 0.f};

    bf16x8 gr[4];
    {
        const unsigned short* p = xb + (((size_t)idx_c) << 7);
#pragma unroll
        for (int qq = 0; qq < 4; ++qq) gr[qq] = *(const bf16x8*)(p + qq * 8);
#pragma unroll
        for (int i = 0; i < 4; ++i) {
            const int n = n0 + i * 16 + (lane >> 2);
            gload16(WT + (size_t)n * Kdim + schunk, &Bs[0][i * 512]);
        }
#pragma unroll
        for (int qq = 0; qq < 4; ++qq) *(bf16x8*)&As[0][sw[qq]] = gr[qq];
    }
    __syncthreads();

    for (int ts = 0; ts < nsteps; ++ts) {
        const int cur = ts & 1, nbuf = cur ^ 1, tn = ts + 1;
        const bool more = tn < nsteps;
        if (more) {
            const int k0 = tn * 32;
            const int sn = k0 >> 7;
            const int idx = (sn != s_c) ? idx_n : idx_c;
            const unsigned short* p = xb + (((size_t)idx) << 7) + (k0 & 127);
#pragma unroll
            for (int qq = 0; qq < 4; ++qq) gr[qq] = *(const bf16x8*)(p + qq * 8);
#pragma unroll
            for (int i = 0; i < 4; ++i) {
                const int n = n0 + i * 16 + (lane >> 2);
                gload16(WT + (size_t)n * Kdim + k0 + schunk, &Bs[nbuf][i * 512]);
            }
            if (sn != s_c) {
                idx_c = idx_n;
                s_c = sn;
                if (s_c + 1 < Ksp) idx_n = ST[(size_t)(s_c + 1) * VT + vg];
            }
        }
        bf16x8 af[4], bg[4];
#pragma unroll
        for (int mt = 0; mt < 4; ++mt)
            af[mt] = *(const bf16x8*)&As[cur][(mt * 16 + lr) * 32 + fslot];
#pragma unroll
        for (int nt = 0; nt < 4; ++nt)
            bg[nt] = *(const bf16x8*)&Bs[cur][(nt * 16 + lr) * 32 + fslot];
#pragma unroll
        for (int mt = 0; mt < 4; ++mt)
#pragma unroll
            for (int nt = 0; nt < 4; ++nt)
                acc[mt][nt] = __builtin_amdgcn_mfma_f32_16x16x32_bf16(
                    af[mt], bg[nt], acc[mt][nt], 0, 0, 0);
        if (more) {
#pragma unroll
            for (int qq = 0; qq < 4; ++qq) *(bf16x8*)&As[nbuf][sw[qq]] = gr[qq];
        }
        __syncthreads();
    }

#pragma unroll
    for (int nt = 0; nt < 4; ++nt) {
        const int n = n0 + nt * 16 + lr;
        const float bv = bias[n];
        unsigned short* op = outT + (size_t)(b * Fout + n) * VP;
#pragma unroll
        for (int mt = 0; mt < 4; ++mt) {
            const int v = v0 + mt * 16 + (lane >> 4) * 4;
            ushort4 stv;
#pragma unroll
            for (int j = 0; j < 4; ++j) {
                float val = acc[mt][nt][j] + bv;
                val = val > 0.f ? val : expm1f(val);
                if (v + j == VT - 1) val = 0.f;
                ((unsigned short*)&stv)[j] = f2bf(val);
            }
            *(ushort4*)(op + v) = stv;
        }
    }
}

// ------- Final conv (Fout=3, Fin=64, K=20): wave per (b,v), bf16 in, fp32 out -------
__global__ __launch_bounds__(256) void spiral_out_kernel(
    const unsigned short* __restrict__ x, const int* __restrict__ S,
    const float* __restrict__ W, const float* __restrict__ bias,
    float* __restrict__ out, int V, int VP) {
    __shared__ float Ws[20 * 64 * 3];
    int t = threadIdx.x;
    for (int i = t; i < 20 * 64 * 3; i += 256) Ws[i] = W[i];
    __syncthreads();

    int gw = (blockIdx.x * 256 + t) >> 6;
    int lane = t & 63;
    int total = NB * V;
    if (gw >= total) return;
    int b = gw / V;
    int v = gw - b * V;

    const unsigned short* xbp = x + ((size_t)b * VP) * 64 + lane;
    const int* Srow = S + (size_t)v * 20;
    float a0 = 0.f, a1 = 0.f, a2 = 0.f;
#pragma unroll
    for (int k = 0; k < 20; ++k) {
        int idx = Srow[k];
        float xv = bff(xbp[(size_t)idx * 64]);
        const float* w = &Ws[(k * 64 + lane) * 3];
        a0 = fmaf(xv, w[0], a0);
        a1 = fmaf(xv, w[1], a1);
        a2 = fmaf(xv, w[2], a2);
    }
#pragma unroll
    for (int off = 32; off > 0; off >>= 1) {
        a0 += __shfl_down(a0, off);
        a1 += __shfl_down(a1, off);
        a2 += __shfl_down(a2, off);
    }
    if (lane == 0) {
        size_t o = (size_t)gw * 3;
        if (v == V - 1) {
            out[o] = 0.f; out[o + 1] = 0.f; out[o + 2] = 0.f;
        } else {
            out[o]     = a0 + bias[0];
            out[o + 1] = a1 + bias[1];
            out[o + 2] = a2 + bias[2];
        }
    }
}

extern "C" void kernel_launch(void* const* d_in, const int* in_sizes, int n_in,
                              void* d_out, int out_size, void* d_ws, size_t ws_size,
                              hipStream_t stream) {
    const float* z   = (const float*)d_in[0];
    const float* U0  = (const float*)d_in[1];
    const float* U1  = (const float*)d_in[2];
    const float* U2  = (const float*)d_in[3];
    const int*   S0  = (const int*)d_in[4];
    const int*   S1  = (const int*)d_in[5];
    const int*   S2  = (const int*)d_in[6];
    const float* Wfc = (const float*)d_in[7];
    const float* bfc = (const float*)d_in[8];
    const float* W0  = (const float*)d_in[9];
    const float* b0  = (const float*)d_in[10];
    const float* W1  = (const float*)d_in[11];
    const float* b1  = (const float*)d_in[12];
    const float* W2  = (const float*)d_in[13];
    const float* b2  = (const float*)d_in[14];
    float* out = (float*)d_out;

    char* ws = (char*)d_ws;
    unsigned short* Ub0 = (unsigned short*)(ws + 0);          // [11904][2976]
    unsigned short* Ub1 = (unsigned short*)(ws + 70852608);   // [3072][768]
    unsigned short* Ub2 = (unsigned short*)(ws + 75571200);   // [768][192]
    unsigned short* x3T = (unsigned short*)(ws + 75866112);   // [2048][192]
    unsigned short* x2u = (unsigned short*)(ws + 76652544);   // [16][768][128]
    unsigned short* x2T = (unsigned short*)(ws + 79798272);   // [2048][768]
    unsigned short* x1u = (unsigned short*)(ws + 82944000);   // [16][3072][128]
    unsigned short* x1T = (unsigned short*)(ws + 95526912);   // [1024][3072]
    unsigned short* x0u = (unsigned short*)(ws + 101818368);  // [16][11904][64]
    unsigned short* W0T = (unsigned short*)(ws + 126197760);  // [128][1536]
    unsigned short* W1T = (unsigned short*)(ws + 126590976);  // [64][1792]
    int* S1T = (int*)(ws + 126820352);                        // [14][2949]
    int* S2T = (int*)(ws + 126985504);                        // [12][738]

    // converters (once per call)
    cvt_ub<<<dim3(12, 11904), 256, 0, stream>>>(U0, Ub0, 11794, 2949, 2976);
    cvt_ub<<<dim3(3, 3072), 256, 0, stream>>>(U1, Ub1, 2949, 738, 768);
    cvt_ub<<<dim3(1, 768), 256, 0, stream>>>(U2, Ub2, 738, 185, 192);
    cvt_wT<<<dim3((128 * 1536 + 255) / 256), 256, 0, stream>>>(W0, W0T, 1536, 128, 128 * 1536);
    cvt_wT<<<dim3((64 * 1792 + 255) / 256), 256, 0, stream>>>(W1, W1T, 1792, 64, 64 * 1792);
    cvt_sT<<<dim3((14 * 2949 + 255) / 256), 256, 0, stream>>>(S1, S1T, 2949, 14, 14 * 2949);
    cvt_sT<<<dim3((12 * 738 + 255) / 256), 256, 0, stream>>>(S2, S2T, 738, 12, 12 * 738);
    zero16<<<dim3(192), 256, 0, stream>>>((int4*)x3T, 2048 * 192 * 2 / 16);

    // 1. FC -> x3T
    fc_kernel<<<dim3((185 * 128 + 255) / 256), 256, 0, stream>>>(z, Wfc, bfc, x3T);
    // 2. U2 upsample -> x2u : grid 6*16=96, strides (192,192), 6 steps
    ups_mfma<7, 768><<<dim3(96), 256, 0, stream>>>(Ub2, x3T, x2u, 192, 192, 6, 4, 12);
    // 3. conv0 (K=12,128->128,elu) -> x2T
    conv_mfma<768><<<dim3(192, 2), 64, 0, stream>>>(x2u, S2T, W0T, b0, x2T, 738, 12, 1536, 48, 128);
    // 4. U1 upsample -> x1u : grid 24*16=384, strides (768,768), 24 steps
    ups_mfma<7, 3072><<<dim3(384), 256, 0, stream>>>(Ub1, x2T, x1u, 768, 768, 24, 4, 48);
    // 5. conv1 (K=14,128->64,elu) -> x1T
    conv_mfma<3072><<<dim3(768, 1), 64, 0, stream>>>(x1u, S1T, W1T, b1, x1T, 2949, 14, 1792, 56, 64);
    // 6. U0 upsample -> x0u : grid 93*8=744, strides (Ub0=2976, x1T=3072), 93 steps
    ups_mfma<6, 11904><<<dim3(744), 256, 0, stream>>>(Ub0, x1T, x0u, 2976, 3072, 93, 3, 93);
    // 7. conv2 (K=20, 64->3, fp32 out) -> d_out
    spiral_out_kernel<<<dim3((NB * 11794 * 64 + 255) / 256), 256, 0, stream>>>(
        x0u, S0, W2, b2, out, 11794, 11904);
}

// Round 7
// 401.415 us; speedup vs baseline: 1.1410x; 1.1410x over previous
//
#include <hip/hip_runtime.h>
#include <cmath>

// Decoder_spirals R6: R5 + final conv rewritten as gathered MFMA GEMM (out_mfma).
// M = 16*11794 (64-row 1-wave tiles), N = 16 (W2 padded 3->16, bf16 [16][1288]),
// K = 1280, BK = 32 dbuf. B-frag register-double-buffered straight from global
// (41KB L2-resident). Replaces wave-per-vertex shuffle-reduce kernel (160us,
// VALUBusy 64% pure-overhead).

#define NB 16

typedef __attribute__((ext_vector_type(8))) short bf16x8;
typedef __attribute__((ext_vector_type(4))) float f32x4;

__device__ __forceinline__ unsigned short f2bf(float x) {
    union { float f; unsigned u; } v; v.f = x;
    unsigned r = v.u + 0x7FFFu + ((v.u >> 16) & 1u);
    return (unsigned short)(r >> 16);
}
__device__ __forceinline__ void gload16(const void* src, void* dst) {
    __builtin_amdgcn_global_load_lds(
        (const __attribute__((address_space(1))) unsigned int*)src,
        (__attribute__((address_space(3))) unsigned int*)dst, 16, 0, 0);
}

// ---------------- converters ----------------
__global__ __launch_bounds__(256) void cvt_ub(const float* __restrict__ src,
                                              unsigned short* __restrict__ dst,
                                              int V, int W, int Wp) {
    int k = blockIdx.x * 256 + threadIdx.x;
    int row = blockIdx.y;
    if (k >= Wp) return;
    float v = (row < V && k < W) ? src[(size_t)row * W + k] : 0.f;
    dst[(size_t)row * Wp + k] = f2bf(v);
}
__global__ __launch_bounds__(256) void cvt_wT(const float* __restrict__ w,
                                              unsigned short* __restrict__ wT,
                                              int K, int N, int total) {
    int id = blockIdx.x * 256 + threadIdx.x;
    if (id >= total) return;
    int n = id / K, k = id - n * K;
    wT[id] = f2bf(w[(size_t)k * N + n]);
}
__global__ __launch_bounds__(256) void cvt_w2(const float* __restrict__ w,
                                              unsigned short* __restrict__ wt) {
    int id = blockIdx.x * 256 + threadIdx.x;
    if (id >= 16 * 1288) return;
    int n = id / 1288, k = id - n * 1288;
    float v = (n < 3 && k < 1280) ? w[(size_t)k * 3 + n] : 0.f;
    wt[id] = f2bf(v);
}
__global__ __launch_bounds__(256) void cvt_sT(const int* __restrict__ S,
                                              int* __restrict__ ST,
                                              int V, int K, int total) {
    int id = blockIdx.x * 256 + threadIdx.x;
    if (id >= total) return;
    int k = id / V, v = id - k * V;
    ST[id] = S[(size_t)v * K + k];
}
__global__ __launch_bounds__(256) void zero16(int4* __restrict__ p, int n16) {
    int id = blockIdx.x * 256 + threadIdx.x;
    if (id < n16) p[id] = make_int4(0, 0, 0, 0);
}

// ---------------- FC: z(16,128)@Wfc(128,23680)+bfc -> x3T[b*128+f][192] bf16 ----------------
__global__ __launch_bounds__(256) void fc_kernel(const float* __restrict__ z,
                                                 const float* __restrict__ Wfc,
                                                 const float* __restrict__ bfc,
                                                 unsigned short* __restrict__ x3T) {
    const int N = 185 * 128;
    __shared__ float zs[NB * 128];
    int t = threadIdx.x;
    for (int i = t; i < NB * 128; i += 256) zs[i] = z[i];
    __syncthreads();
    int n = blockIdx.x * 256 + t;
    if (n >= N) return;
    float acc[NB];
#pragma unroll
    for (int b = 0; b < NB; ++b) acc[b] = 0.f;
    for (int k = 0; k < 128; ++k) {
        float w = Wfc[k * N + n];
#pragma unroll
        for (int b = 0; b < NB; ++b) acc[b] = fmaf(zs[b * 128 + k], w, acc[b]);
    }
    float bv = bfc[n];
    int f = n & 127, v = n >> 7;
#pragma unroll
    for (int b = 0; b < NB; ++b)
        x3T[(size_t)(b * 128 + f) * 192 + v] = f2bf(acc[b] + bv);
}

// ------------- Upsample: out[b,v,f] = sum_w U[v,w]*x[b,w,f] -------------
template<int FSH, int VP>
__global__ __launch_bounds__(256) void ups_mfma(
    const unsigned short* __restrict__ Ub, const unsigned short* __restrict__ xT,
    unsigned short* __restrict__ out,
    int WpA, int WpB, int nsteps, int gxsh, int q) {
    const int F = 1 << FSH;
    __shared__ __align__(16) unsigned short As[2][128 * 32];
    __shared__ __align__(16) unsigned short Bs[2][128 * 32];
    const int t = threadIdx.x;
    const int wv = t >> 6, lane = t & 63;
    const int lr = lane & 15;

    const int flat = blockIdx.x;
    const int wg = (flat & 7) * q + (flat >> 3);
    const int m0 = (wg >> gxsh) * 128;
    const int n0 = (wg & ((1 << gxsh) - 1)) * 128;

    const int srow = lane >> 2;
    const int schunk = (((lane & 3) - ((lane >> 3) & 3)) & 3) * 8;
    const unsigned short* asrc[2];
    const unsigned short* bsrc[2];
#pragma unroll
    for (int i = 0; i < 2; ++i) {
        const int ii = wv * 2 + i;
        asrc[i] = Ub + (size_t)(m0 + ii * 16 + srow) * WpA + schunk;
        bsrc[i] = xT + (size_t)(n0 + ii * 16 + srow) * WpB + schunk;
    }
    const int fslot = (((lane >> 4) + (lr >> 1)) & 3) * 8;
    const int wrow = (wv >> 1) * 64;
    const int wcol = (wv & 1) * 64;

    f32x4 acc[4][4];
#pragma unroll
    for (int i = 0; i < 4; ++i)
#pragma unroll
        for (int j = 0; j < 4; ++j) acc[i][j] = {0.f, 0.f, 0.f, 0.f};

#pragma unroll
    for (int i = 0; i < 2; ++i) {
        const int ii = wv * 2 + i;
        gload16(asrc[i], &As[0][ii * 512]);
        gload16(bsrc[i], &Bs[0][ii * 512]);
    }
    __syncthreads();

    for (int ts = 0; ts < nsteps; ++ts) {
        const int cur = ts & 1, nbuf = cur ^ 1, tn = ts + 1;
        if (tn < nsteps) {
            const int k0 = tn * 32;
#pragma unroll
            for (int i = 0; i < 2; ++i) {
                const int ii = wv * 2 + i;
                gload16(asrc[i] + k0, &As[nbuf][ii * 512]);
                gload16(bsrc[i] + k0, &Bs[nbuf][ii * 512]);
            }
        }
        bf16x8 af[4], bg[4];
#pragma unroll
        for (int mt = 0; mt < 4; ++mt)
            af[mt] = *(const bf16x8*)&As[cur][(wrow + mt * 16 + lr) * 32 + fslot];
#pragma unroll
        for (int nt = 0; nt < 4; ++nt)
            bg[nt] = *(const bf16x8*)&Bs[cur][(wcol + nt * 16 + lr) * 32 + fslot];
#pragma unroll
        for (int mt = 0; mt < 4; ++mt)
#pragma unroll
            for (int nt = 0; nt < 4; ++nt)
                acc[mt][nt] = __builtin_amdgcn_mfma_f32_16x16x32_bf16(
                    af[mt], bg[nt], acc[mt][nt], 0, 0, 0);
        __syncthreads();
    }

#pragma unroll
    for (int mt = 0; mt < 4; ++mt) {
        const int vb = m0 + wrow + mt * 16 + (lane >> 4) * 4;
#pragma unroll
        for (int nt = 0; nt < 4; ++nt) {
            const int col = n0 + wcol + nt * 16 + lr;
            const int b = col >> FSH, f = col & (F - 1);
            unsigned short* op = out + (size_t)b * VP * F + f;
#pragma unroll
            for (int j = 0; j < 4; ++j)
                op[(size_t)(vb + j) * F] = f2bf(acc[mt][nt][j]);
        }
    }
}

// ------- SpiralConv: gathered-A bf16 GEMM + bias + ELU + zero dummy, transposed out -------
template<int VP>
__global__ __launch_bounds__(64) void conv_mfma(
    const unsigned short* __restrict__ xu, const int* __restrict__ ST,
    const unsigned short* __restrict__ WT, const float* __restrict__ bias,
    unsigned short* __restrict__ outT,
    int VT, int Ksp, int Kdim, int nsteps, int Fout) {
    __shared__ __align__(16) unsigned short As[2][64 * 32];
    __shared__ __align__(16) unsigned short Bs[2][64 * 32];
    const int lane = threadIdx.x;
    const int lr = lane & 15;
    const int m0 = blockIdx.x * 64;
    const int n0 = blockIdx.y * 64;
    const int b = m0 / VP;
    const int v0 = m0 - b * VP;
    const unsigned short* xb = xu + (((size_t)b * VP) << 7);

    const int vg = (v0 + lane < VT) ? (v0 + lane) : (VT - 1);
    const int schunk = (((lane & 3) - ((lane >> 3) & 3)) & 3) * 8;
    const int fslot = (((lane >> 4) + (lr >> 1)) & 3) * 8;
    int sw[4];
#pragma unroll
    for (int qq = 0; qq < 4; ++qq)
        sw[qq] = lane * 32 + (((qq + ((lane >> 1) & 3)) & 3) * 8);

    int s_c = 0;
    int idx_c = ST[vg];
    int idx_n = ST[(size_t)VT + vg];

    f32x4 acc[4][4];
#pragma unroll
    for (int i = 0; i < 4; ++i)
#pragma unroll
        for (int j = 0; j < 4; ++j) acc[i][j] = {0.f, 0.f, 0.f, 0.f};

    bf16x8 gr[4];
    {
        const unsigned short* p = xb + (((size_t)idx_c) << 7);
#pragma unroll
        for (int qq = 0; qq < 4; ++qq) gr[qq] = *(const bf16x8*)(p + qq * 8);
#pragma unroll
        for (int i = 0; i < 4; ++i) {
            const int n = n0 + i * 16 + (lane >> 2);
            gload16(WT + (size_t)n * Kdim + schunk, &Bs[0][i * 512]);
        }
#pragma unroll
        for (int qq = 0; qq < 4; ++qq) *(bf16x8*)&As[0][sw[qq]] = gr[qq];
    }
    __syncthreads();

    for (int ts = 0; ts < nsteps; ++ts) {
        const int cur = ts & 1, nbuf = cur ^ 1, tn = ts + 1;
        const bool more = tn < nsteps;
        if (more) {
            const int k0 = tn * 32;
            const int sn = k0 >> 7;
            const int idx = (sn != s_c) ? idx_n : idx_c;
            const unsigned short* p = xb + (((size_t)idx) << 7) + (k0 & 127);
#pragma unroll
            for (int qq = 0; qq < 4; ++qq) gr[qq] = *(const bf16x8*)(p + qq * 8);
#pragma unroll
            for (int i = 0; i < 4; ++i) {
                const int n = n0 + i * 16 + (lane >> 2);
                gload16(WT + (size_t)n * Kdim + k0 + schunk, &Bs[nbuf][i * 512]);
            }
            if (sn != s_c) {
                idx_c = idx_n;
                s_c = sn;
                if (s_c + 1 < Ksp) idx_n = ST[(size_t)(s_c + 1) * VT + vg];
            }
        }
        bf16x8 af[4], bg[4];
#pragma unroll
        for (int mt = 0; mt < 4; ++mt)
            af[mt] = *(const bf16x8*)&As[cur][(mt * 16 + lr) * 32 + fslot];
#pragma unroll
        for (int nt = 0; nt < 4; ++nt)
            bg[nt] = *(const bf16x8*)&Bs[cur][(nt * 16 + lr) * 32 + fslot];
#pragma unroll
        for (int mt = 0; mt < 4; ++mt)
#pragma unroll
            for (int nt = 0; nt < 4; ++nt)
                acc[mt][nt] = __builtin_amdgcn_mfma_f32_16x16x32_bf16(
                    af[mt], bg[nt], acc[mt][nt], 0, 0, 0);
        if (more) {
#pragma unroll
            for (int qq = 0; qq < 4; ++qq) *(bf16x8*)&As[nbuf][sw[qq]] = gr[qq];
        }
        __syncthreads();
    }

#pragma unroll
    for (int nt = 0; nt < 4; ++nt) {
        const int n = n0 + nt * 16 + lr;
        const float bv = bias[n];
        unsigned short* op = outT + (size_t)(b * Fout + n) * VP;
#pragma unroll
        for (int mt = 0; mt < 4; ++mt) {
            const int v = v0 + mt * 16 + (lane >> 4) * 4;
            ushort4 stv;
#pragma unroll
            for (int j = 0; j < 4; ++j) {
                float val = acc[mt][nt][j] + bv;
                val = val > 0.f ? val : expm1f(val);
                if (v + j == VT - 1) val = 0.f;
                ((unsigned short*)&stv)[j] = f2bf(val);
            }
            *(ushort4*)(op + v) = stv;
        }
    }
}

// ------- Final conv as MFMA: M=16*11794 (64-row tiles), N=16 (3 used), K=1280 -------
// A: gathered x0u rows (bf16, Fin=64, 32k chunk per step); B: W2T [16][1288] from
// global, register-dbuf. Epilogue: fp32 + bias, dummy vertex zeroed, lanes lr<3 store.
__global__ __launch_bounds__(64) void out_mfma(
    const unsigned short* __restrict__ xu, const int* __restrict__ ST,
    const unsigned short* __restrict__ W2T, const float* __restrict__ b2,
    float* __restrict__ out) {
    const int VT = 11794, VP = 11904, TPB = 186;
    __shared__ __align__(16) unsigned short As[2][64 * 32];
    const int lane = threadIdx.x;
    const int lr = lane & 15;
    const int lko = (lane >> 4) * 8;
    const int bm = blockIdx.x;
    const int b = bm / TPB;
    const int v0 = (bm - b * TPB) * 64;
    const unsigned short* xb = xu + ((size_t)b * VP << 6);

    const int v = v0 + lane;
    const int vg = v < VT ? v : VT - 1;
    int sw[4];
#pragma unroll
    for (int qq = 0; qq < 4; ++qq)
        sw[qq] = lane * 32 + (((qq + ((lane >> 1) & 3)) & 3) * 8);
    const int fslot = (((lane >> 4) + (lr >> 1)) & 3) * 8;

    int s_c = 0;
    int idx_c = ST[vg];
    int idx_n = ST[VT + vg];

    f32x4 acc[4];
#pragma unroll
    for (int i = 0; i < 4; ++i) acc[i] = {0.f, 0.f, 0.f, 0.f};

    const unsigned short* wrow = W2T + (size_t)lr * 1288 + lko;
    bf16x8 bg_c = *(const bf16x8*)(wrow);
    bf16x8 gr[4];
    {
        const unsigned short* p = xb + ((size_t)idx_c << 6);
#pragma unroll
        for (int qq = 0; qq < 4; ++qq) gr[qq] = *(const bf16x8*)(p + qq * 8);
#pragma unroll
        for (int qq = 0; qq < 4; ++qq) *(bf16x8*)&As[0][sw[qq]] = gr[qq];
    }
    __syncthreads();

    const int nsteps = 40;
    for (int ts = 0; ts < nsteps; ++ts) {
        const int cur = ts & 1, nbuf = cur ^ 1, tn = ts + 1;
        const bool more = tn < nsteps;
        bf16x8 bg_n;
        if (more) {
            const int k0 = tn * 32;
            const int sn = k0 >> 6;
            const int idx = (sn != s_c) ? idx_n : idx_c;
            const unsigned short* p = xb + ((size_t)idx << 6) + (k0 & 63);
#pragma unroll
            for (int qq = 0; qq < 4; ++qq) gr[qq] = *(const bf16x8*)(p + qq * 8);
            bg_n = *(const bf16x8*)(wrow + k0);
            if (sn != s_c) {
                idx_c = idx_n;
                s_c = sn;
                if (s_c + 1 < 20) idx_n = ST[(size_t)(s_c + 1) * VT + vg];
            }
        }
        bf16x8 af[4];
#pragma unroll
        for (int mt = 0; mt < 4; ++mt)
            af[mt] = *(const bf16x8*)&As[cur][(mt * 16 + lr) * 32 + fslot];
#pragma unroll
        for (int mt = 0; mt < 4; ++mt)
            acc[mt] = __builtin_amdgcn_mfma_f32_16x16x32_bf16(af[mt], bg_c, acc[mt], 0, 0, 0);
        if (more) {
#pragma unroll
            for (int qq = 0; qq < 4; ++qq) *(bf16x8*)&As[nbuf][sw[qq]] = gr[qq];
            bg_c = bg_n;
        }
        __syncthreads();
    }

    if (lr < 3) {
        const float bv = b2[lr];
#pragma unroll
        for (int mt = 0; mt < 4; ++mt) {
#pragma unroll
            for (int j = 0; j < 4; ++j) {
                const int vv = v0 + mt * 16 + (lane >> 4) * 4 + j;
                if (vv < VT) {
                    float val = acc[mt][j] + bv;
                    if (vv == VT - 1) val = 0.f;
                    out[((size_t)b * VT + vv) * 3 + lr] = val;
                }
            }
        }
    }
}

extern "C" void kernel_launch(void* const* d_in, const int* in_sizes, int n_in,
                              void* d_out, int out_size, void* d_ws, size_t ws_size,
                              hipStream_t stream) {
    const float* z   = (const float*)d_in[0];
    const float* U0  = (const float*)d_in[1];
    const float* U1  = (const float*)d_in[2];
    const float* U2  = (const float*)d_in[3];
    const int*   S0  = (const int*)d_in[4];
    const int*   S1  = (const int*)d_in[5];
    const int*   S2  = (const int*)d_in[6];
    const float* Wfc = (const float*)d_in[7];
    const float* bfc = (const float*)d_in[8];
    const float* W0  = (const float*)d_in[9];
    const float* b0  = (const float*)d_in[10];
    const float* W1  = (const float*)d_in[11];
    const float* b1  = (const float*)d_in[12];
    const float* W2  = (const float*)d_in[13];
    const float* b2  = (const float*)d_in[14];
    float* out = (float*)d_out;

    char* ws = (char*)d_ws;
    unsigned short* Ub0 = (unsigned short*)(ws + 0);          // [11904][2976]
    unsigned short* Ub1 = (unsigned short*)(ws + 70852608);   // [3072][768]
    unsigned short* Ub2 = (unsigned short*)(ws + 75571200);   // [768][192]
    unsigned short* x3T = (unsigned short*)(ws + 75866112);   // [2048][192]
    unsigned short* x2u = (unsigned short*)(ws + 76652544);   // [16][768][128]
    unsigned short* x2T = (unsigned short*)(ws + 79798272);   // [2048][768]
    unsigned short* x1u = (unsigned short*)(ws + 82944000);   // [16][3072][128]
    unsigned short* x1T = (unsigned short*)(ws + 95526912);   // [1024][3072]
    unsigned short* x0u = (unsigned short*)(ws + 101818368);  // [16][11904][64]
    unsigned short* W0T = (unsigned short*)(ws + 126197760);  // [128][1536]
    unsigned short* W1T = (unsigned short*)(ws + 126590976);  // [64][1792]
    int* S1T = (int*)(ws + 126820352);                        // [14][2949]
    int* S2T = (int*)(ws + 126985504);                        // [12][738]
    int* S0T = (int*)(ws + 127020928);                        // [20][11794]
    unsigned short* W2T = (unsigned short*)(ws + 127964448);  // [16][1288]

    // converters (once per call)
    cvt_ub<<<dim3(12, 11904), 256, 0, stream>>>(U0, Ub0, 11794, 2949, 2976);
    cvt_ub<<<dim3(3, 3072), 256, 0, stream>>>(U1, Ub1, 2949, 738, 768);
    cvt_ub<<<dim3(1, 768), 256, 0, stream>>>(U2, Ub2, 738, 185, 192);
    cvt_wT<<<dim3((128 * 1536 + 255) / 256), 256, 0, stream>>>(W0, W0T, 1536, 128, 128 * 1536);
    cvt_wT<<<dim3((64 * 1792 + 255) / 256), 256, 0, stream>>>(W1, W1T, 1792, 64, 64 * 1792);
    cvt_w2<<<dim3((16 * 1288 + 255) / 256), 256, 0, stream>>>(W2, W2T);
    cvt_sT<<<dim3((14 * 2949 + 255) / 256), 256, 0, stream>>>(S1, S1T, 2949, 14, 14 * 2949);
    cvt_sT<<<dim3((12 * 738 + 255) / 256), 256, 0, stream>>>(S2, S2T, 738, 12, 12 * 738);
    cvt_sT<<<dim3((20 * 11794 + 255) / 256), 256, 0, stream>>>(S0, S0T, 11794, 20, 20 * 11794);
    zero16<<<dim3(192), 256, 0, stream>>>((int4*)x3T, 2048 * 192 * 2 / 16);

    // 1. FC -> x3T
    fc_kernel<<<dim3((185 * 128 + 255) / 256), 256, 0, stream>>>(z, Wfc, bfc, x3T);
    // 2. U2 upsample -> x2u
    ups_mfma<7, 768><<<dim3(96), 256, 0, stream>>>(Ub2, x3T, x2u, 192, 192, 6, 4, 12);
    // 3. conv0 (K=12,128->128,elu) -> x2T
    conv_mfma<768><<<dim3(192, 2), 64, 0, stream>>>(x2u, S2T, W0T, b0, x2T, 738, 12, 1536, 48, 128);
    // 4. U1 upsample -> x1u
    ups_mfma<7, 3072><<<dim3(384), 256, 0, stream>>>(Ub1, x2T, x1u, 768, 768, 24, 4, 48);
    // 5. conv1 (K=14,128->64,elu) -> x1T
    conv_mfma<3072><<<dim3(768, 1), 64, 0, stream>>>(x1u, S1T, W1T, b1, x1T, 2949, 14, 1792, 56, 64);
    // 6. U0 upsample -> x0u
    ups_mfma<6, 11904><<<dim3(744), 256, 0, stream>>>(Ub0, x1T, x0u, 2976, 3072, 93, 3, 93);
    // 7. conv2 (K=20, 64->3) as MFMA GEMM -> d_out
    out_mfma<<<dim3(16 * 186), 64, 0, stream>>>(x0u, S0T, W2T, b2, out);
}

// Round 8
// 398.422 us; speedup vs baseline: 1.1495x; 1.0075x over previous
//
#include <hip/hip_runtime.h>
#include <cmath>

// Decoder_spirals R7:
// - ups_mfma: 3-buffer LDS, 2-deep prefetch, counted s_waitcnt vmcnt(4) + raw
//   s_barrier (never drain-to-0 in main loop) -- T3/T4-lite.
// - conv_mfma / out_mfma: 32-row 1-wave tiles (2x grid -> 2x occupancy).
// Everything else as R6 (all-gload bf16 MFMA, add-perm LDS swizzle, bf16 ws).

#define NB 16

typedef __attribute__((ext_vector_type(8))) short bf16x8;
typedef __attribute__((ext_vector_type(4))) float f32x4;

__device__ __forceinline__ unsigned short f2bf(float x) {
    union { float f; unsigned u; } v; v.f = x;
    unsigned r = v.u + 0x7FFFu + ((v.u >> 16) & 1u);
    return (unsigned short)(r >> 16);
}
__device__ __forceinline__ void gload16(const void* src, void* dst) {
    __builtin_amdgcn_global_load_lds(
        (const __attribute__((address_space(1))) unsigned int*)src,
        (__attribute__((address_space(3))) unsigned int*)dst, 16, 0, 0);
}

// ---------------- converters ----------------
__global__ __launch_bounds__(256) void cvt_ub(const float* __restrict__ src,
                                              unsigned short* __restrict__ dst,
                                              int V, int W, int Wp) {
    int k = blockIdx.x * 256 + threadIdx.x;
    int row = blockIdx.y;
    if (k >= Wp) return;
    float v = (row < V && k < W) ? src[(size_t)row * W + k] : 0.f;
    dst[(size_t)row * Wp + k] = f2bf(v);
}
__global__ __launch_bounds__(256) void cvt_wT(const float* __restrict__ w,
                                              unsigned short* __restrict__ wT,
                                              int K, int N, int total) {
    int id = blockIdx.x * 256 + threadIdx.x;
    if (id >= total) return;
    int n = id / K, k = id - n * K;
    wT[id] = f2bf(w[(size_t)k * N + n]);
}
__global__ __launch_bounds__(256) void cvt_w2(const float* __restrict__ w,
                                              unsigned short* __restrict__ wt) {
    int id = blockIdx.x * 256 + threadIdx.x;
    if (id >= 16 * 1288) return;
    int n = id / 1288, k = id - n * 1288;
    float v = (n < 3 && k < 1280) ? w[(size_t)k * 3 + n] : 0.f;
    wt[id] = f2bf(v);
}
__global__ __launch_bounds__(256) void cvt_sT(const int* __restrict__ S,
                                              int* __restrict__ ST,
                                              int V, int K, int total) {
    int id = blockIdx.x * 256 + threadIdx.x;
    if (id >= total) return;
    int k = id / V, v = id - k * V;
    ST[id] = S[(size_t)v * K + k];
}
__global__ __launch_bounds__(256) void zero16(int4* __restrict__ p, int n16) {
    int id = blockIdx.x * 256 + threadIdx.x;
    if (id < n16) p[id] = make_int4(0, 0, 0, 0);
}

// ---------------- FC: z(16,128)@Wfc(128,23680)+bfc -> x3T[b*128+f][192] bf16 ----------------
__global__ __launch_bounds__(256) void fc_kernel(const float* __restrict__ z,
                                                 const float* __restrict__ Wfc,
                                                 const float* __restrict__ bfc,
                                                 unsigned short* __restrict__ x3T) {
    const int N = 185 * 128;
    __shared__ float zs[NB * 128];
    int t = threadIdx.x;
    for (int i = t; i < NB * 128; i += 256) zs[i] = z[i];
    __syncthreads();
    int n = blockIdx.x * 256 + t;
    if (n >= N) return;
    float acc[NB];
#pragma unroll
    for (int b = 0; b < NB; ++b) acc[b] = 0.f;
    for (int k = 0; k < 128; ++k) {
        float w = Wfc[k * N + n];
#pragma unroll
        for (int b = 0; b < NB; ++b) acc[b] = fmaf(zs[b * 128 + k], w, acc[b]);
    }
    float bv = bfc[n];
    int f = n & 127, v = n >> 7;
#pragma unroll
    for (int b = 0; b < NB; ++b)
        x3T[(size_t)(b * 128 + f) * 192 + v] = f2bf(acc[b] + bv);
}

// ------------- Upsample: out[b,v,f] = sum_w U[v,w]*x[b,w,f] -------------
// 3-buffer pipeline, 2-deep prefetch, counted vmcnt(4), raw s_barrier.
template<int FSH, int VP>
__global__ __launch_bounds__(256) void ups_mfma(
    const unsigned short* __restrict__ Ub, const unsigned short* __restrict__ xT,
    unsigned short* __restrict__ out,
    int WpA, int WpB, int nsteps, int gxsh, int q) {
    const int F = 1 << FSH;
    __shared__ __align__(16) unsigned short As[3][128 * 32];
    __shared__ __align__(16) unsigned short Bs[3][128 * 32];
    const int t = threadIdx.x;
    const int wv = t >> 6, lane = t & 63;
    const int lr = lane & 15;

    const int flat = blockIdx.x;
    const int wg = (flat & 7) * q + (flat >> 3);
    const int m0 = (wg >> gxsh) * 128;
    const int n0 = (wg & ((1 << gxsh) - 1)) * 128;

    const int srow = lane >> 2;
    const int schunk = (((lane & 3) - ((lane >> 3) & 3)) & 3) * 8;
    const unsigned short* asrc[2];
    const unsigned short* bsrc[2];
#pragma unroll
    for (int i = 0; i < 2; ++i) {
        const int ii = wv * 2 + i;
        asrc[i] = Ub + (size_t)(m0 + ii * 16 + srow) * WpA + schunk;
        bsrc[i] = xT + (size_t)(n0 + ii * 16 + srow) * WpB + schunk;
    }
    const int fslot = (((lane >> 4) + (lr >> 1)) & 3) * 8;
    const int wrow = (wv >> 1) * 64;
    const int wcol = (wv & 1) * 64;
    const int u0 = wv * 1024;  // this wave's staging dest offset (2 units x 512)

    f32x4 acc[4][4];
#pragma unroll
    for (int i = 0; i < 4; ++i)
#pragma unroll
        for (int j = 0; j < 4; ++j) acc[i][j] = {0.f, 0.f, 0.f, 0.f};

#define UPS_STAGE(ts_, buf_)                                            \
    {                                                                   \
        const int k0_ = (ts_) * 32;                                     \
        gload16(asrc[0] + k0_, &As[buf_][u0]);                          \
        gload16(bsrc[0] + k0_, &Bs[buf_][u0]);                          \
        gload16(asrc[1] + k0_, &As[buf_][u0 + 512]);                    \
        gload16(bsrc[1] + k0_, &Bs[buf_][u0 + 512]);                    \
    }
#define UPS_COMPUTE(buf_)                                               \
    {                                                                   \
        bf16x8 af[4], bg[4];                                            \
        _Pragma("unroll")                                               \
        for (int mt = 0; mt < 4; ++mt)                                  \
            af[mt] = *(const bf16x8*)&As[buf_][(wrow + mt * 16 + lr) * 32 + fslot]; \
        _Pragma("unroll")                                               \
        for (int nt = 0; nt < 4; ++nt)                                  \
            bg[nt] = *(const bf16x8*)&Bs[buf_][(wcol + nt * 16 + lr) * 32 + fslot]; \
        _Pragma("unroll")                                               \
        for (int mt = 0; mt < 4; ++mt)                                  \
            _Pragma("unroll")                                           \
            for (int nt = 0; nt < 4; ++nt)                              \
                acc[mt][nt] = __builtin_amdgcn_mfma_f32_16x16x32_bf16(  \
                    af[mt], bg[nt], acc[mt][nt], 0, 0, 0);              \
    }

    // prologue: stage steps 0,1
    UPS_STAGE(0, 0);
    UPS_STAGE(1, 1);
    asm volatile("s_waitcnt vmcnt(4)" ::: "memory");
    __builtin_amdgcn_s_barrier();

    int bcur = 0, bnxt = 1, bnx2 = 2;
    int ts = 0;
    for (; ts + 2 < nsteps; ++ts) {
        UPS_STAGE(ts + 2, bnx2);
        UPS_COMPUTE(bcur);
        asm volatile("s_waitcnt vmcnt(4)" ::: "memory");
        __builtin_amdgcn_s_barrier();
        int tmp = bcur; bcur = bnxt; bnxt = bnx2; bnx2 = tmp;
    }
    // ts == nsteps-2
    UPS_COMPUTE(bcur);
    asm volatile("s_waitcnt vmcnt(0)" ::: "memory");
    __builtin_amdgcn_s_barrier();
    UPS_COMPUTE(bnxt);
#undef UPS_STAGE
#undef UPS_COMPUTE

    // epilogue: C row=(lane>>4)*4+j (m), col=lane&15 (n); write bf16 [b][VP][F]
#pragma unroll
    for (int mt = 0; mt < 4; ++mt) {
        const int vb = m0 + wrow + mt * 16 + (lane >> 4) * 4;
#pragma unroll
        for (int nt = 0; nt < 4; ++nt) {
            const int col = n0 + wcol + nt * 16 + lr;
            const int b = col >> FSH, f = col & (F - 1);
            unsigned short* op = out + (size_t)b * VP * F + f;
#pragma unroll
            for (int j = 0; j < 4; ++j)
                op[(size_t)(vb + j) * F] = f2bf(acc[mt][nt][j]);
        }
    }
}

// ------- SpiralConv: gathered-A bf16 GEMM, 32-row 1-wave tiles, Fin=128 -------
// out: xT[(b*Fout+n)][VP] bf16, bias+ELU+zero-dummy fused.
template<int VP>
__global__ __launch_bounds__(64) void conv_mfma(
    const unsigned short* __restrict__ xu, const int* __restrict__ ST,
    const unsigned short* __restrict__ WT, const float* __restrict__ bias,
    unsigned short* __restrict__ outT,
    int VT, int Ksp, int Kdim, int nsteps, int Fout) {
    __shared__ __align__(16) unsigned short As[2][32 * 32];
    __shared__ __align__(16) unsigned short Bs[2][64 * 32];
    const int lane = threadIdx.x;
    const int lr = lane & 15;
    const int m0 = blockIdx.x * 32;
    const int n0 = blockIdx.y * 64;
    const int b = m0 / VP;
    const int v0 = m0 - b * VP;
    const unsigned short* xb = xu + (((size_t)b * VP) << 7);

    const int arow = lane >> 1;          // 0..31
    const int h = lane & 1;              // k-half (16 elems)
    const int vg = (v0 + arow < VT) ? (v0 + arow) : (VT - 1);
    const int schunk = (((lane & 3) - ((lane >> 3) & 3)) & 3) * 8;
    const int fslot = (((lane >> 4) + (lr >> 1)) & 3) * 8;
    int sw[2];
#pragma unroll
    for (int qq = 0; qq < 2; ++qq)
        sw[qq] = arow * 32 + (((2 * h + qq + ((lane >> 2) & 3)) & 3) * 8);

    int s_c = 0;
    int idx_c = ST[vg];
    int idx_n = ST[(size_t)VT + vg];

    f32x4 acc[2][4];
#pragma unroll
    for (int i = 0; i < 2; ++i)
#pragma unroll
        for (int j = 0; j < 4; ++j) acc[i][j] = {0.f, 0.f, 0.f, 0.f};

    bf16x8 gr[2];
    {
        const unsigned short* p = xb + (((size_t)idx_c) << 7) + h * 16;
        gr[0] = *(const bf16x8*)(p);
        gr[1] = *(const bf16x8*)(p + 8);
#pragma unroll
        for (int i = 0; i < 4; ++i) {
            const int n = n0 + i * 16 + (lane >> 2);
            gload16(WT + (size_t)n * Kdim + schunk, &Bs[0][i * 512]);
        }
        *(bf16x8*)&As[0][sw[0]] = gr[0];
        *(bf16x8*)&As[0][sw[1]] = gr[1];
    }
    __syncthreads();

    for (int ts = 0; ts < nsteps; ++ts) {
        const int cur = ts & 1, nbuf = cur ^ 1, tn = ts + 1;
        const bool more = tn < nsteps;
        if (more) {
            const int k0 = tn * 32;
            const int sn = k0 >> 7;
            const int idx = (sn != s_c) ? idx_n : idx_c;
            const unsigned short* p = xb + (((size_t)idx) << 7) + (k0 & 127) + h * 16;
            gr[0] = *(const bf16x8*)(p);
            gr[1] = *(const bf16x8*)(p + 8);
#pragma unroll
            for (int i = 0; i < 4; ++i) {
                const int n = n0 + i * 16 + (lane >> 2);
                gload16(WT + (size_t)n * Kdim + k0 + schunk, &Bs[nbuf][i * 512]);
            }
            if (sn != s_c) {
                idx_c = idx_n;
                s_c = sn;
                if (s_c + 1 < Ksp) idx_n = ST[(size_t)(s_c + 1) * VT + vg];
            }
        }
        bf16x8 af[2], bg[4];
#pragma unroll
        for (int mt = 0; mt < 2; ++mt)
            af[mt] = *(const bf16x8*)&As[cur][(mt * 16 + lr) * 32 + fslot];
#pragma unroll
        for (int nt = 0; nt < 4; ++nt)
            bg[nt] = *(const bf16x8*)&Bs[cur][(nt * 16 + lr) * 32 + fslot];
#pragma unroll
        for (int mt = 0; mt < 2; ++mt)
#pragma unroll
            for (int nt = 0; nt < 4; ++nt)
                acc[mt][nt] = __builtin_amdgcn_mfma_f32_16x16x32_bf16(
                    af[mt], bg[nt], acc[mt][nt], 0, 0, 0);
        if (more) {
            *(bf16x8*)&As[nbuf][sw[0]] = gr[0];
            *(bf16x8*)&As[nbuf][sw[1]] = gr[1];
        }
        __syncthreads();
    }

#pragma unroll
    for (int nt = 0; nt < 4; ++nt) {
        const int n = n0 + nt * 16 + lr;
        const float bv = bias[n];
        unsigned short* op = outT + (size_t)(b * Fout + n) * VP;
#pragma unroll
        for (int mt = 0; mt < 2; ++mt) {
            const int v = v0 + mt * 16 + (lane >> 4) * 4;
            ushort4 stv;
#pragma unroll
            for (int j = 0; j < 4; ++j) {
                float val = acc[mt][nt][j] + bv;
                val = val > 0.f ? val : expm1f(val);
                if (v + j == VT - 1) val = 0.f;
                ((unsigned short*)&stv)[j] = f2bf(val);
            }
            *(ushort4*)(op + v) = stv;
        }
    }
}

// ------- Final conv as MFMA: 32-row 1-wave tiles, N=16 (3 used), K=1280 -------
__global__ __launch_bounds__(64) void out_mfma(
    const unsigned short* __restrict__ xu, const int* __restrict__ ST,
    const unsigned short* __restrict__ W2T, const float* __restrict__ b2,
    float* __restrict__ out) {
    const int VT = 11794, VP = 11904, TPB = 372;
    __shared__ __align__(16) unsigned short As[2][32 * 32];
    const int lane = threadIdx.x;
    const int lr = lane & 15;
    const int lko = (lane >> 4) * 8;
    const int bm = blockIdx.x;
    const int b = bm / TPB;
    const int v0 = (bm - b * TPB) * 32;
    const unsigned short* xb = xu + ((size_t)b * VP << 6);

    const int arow = lane >> 1;
    const int h = lane & 1;
    const int v = v0 + arow;
    const int vg = v < VT ? v : VT - 1;
    int sw[2];
#pragma unroll
    for (int qq = 0; qq < 2; ++qq)
        sw[qq] = arow * 32 + (((2 * h + qq + ((lane >> 2) & 3)) & 3) * 8);
    const int fslot = (((lane >> 4) + (lr >> 1)) & 3) * 8;

    int s_c = 0;
    int idx_c = ST[vg];
    int idx_n = ST[VT + vg];

    f32x4 acc[2];
#pragma unroll
    for (int i = 0; i < 2; ++i) acc[i] = {0.f, 0.f, 0.f, 0.f};

    const unsigned short* wrow = W2T + (size_t)lr * 1288 + lko;
    bf16x8 bg_c = *(const bf16x8*)(wrow);
    bf16x8 gr[2];
    {
        const unsigned short* p = xb + ((size_t)idx_c << 6) + h * 16;
        gr[0] = *(const bf16x8*)(p);
        gr[1] = *(const bf16x8*)(p + 8);
        *(bf16x8*)&As[0][sw[0]] = gr[0];
        *(bf16x8*)&As[0][sw[1]] = gr[1];
    }
    __syncthreads();

    const int nsteps = 40;
    for (int ts = 0; ts < nsteps; ++ts) {
        const int cur = ts & 1, nbuf = cur ^ 1, tn = ts + 1;
        const bool more = tn < nsteps;
        bf16x8 bg_n;
        if (more) {
            const int k0 = tn * 32;
            const int sn = k0 >> 6;
            const int idx = (sn != s_c) ? idx_n : idx_c;
            const unsigned short* p = xb + ((size_t)idx << 6) + (k0 & 63) + h * 16;
            gr[0] = *(const bf16x8*)(p);
            gr[1] = *(const bf16x8*)(p + 8);
            bg_n = *(const bf16x8*)(wrow + k0);
            if (sn != s_c) {
                idx_c = idx_n;
                s_c = sn;
                if (s_c + 1 < 20) idx_n = ST[(size_t)(s_c + 1) * VT + vg];
            }
        }
        bf16x8 af[2];
#pragma unroll
        for (int mt = 0; mt < 2; ++mt)
            af[mt] = *(const bf16x8*)&As[cur][(mt * 16 + lr) * 32 + fslot];
#pragma unroll
        for (int mt = 0; mt < 2; ++mt)
            acc[mt] = __builtin_amdgcn_mfma_f32_16x16x32_bf16(af[mt], bg_c, acc[mt], 0, 0, 0);
        if (more) {
            *(bf16x8*)&As[nbuf][sw[0]] = gr[0];
            *(bf16x8*)&As[nbuf][sw[1]] = gr[1];
            bg_c = bg_n;
        }
        __syncthreads();
    }

    if (lr < 3) {
        const float bv = b2[lr];
#pragma unroll
        for (int mt = 0; mt < 2; ++mt) {
#pragma unroll
            for (int j = 0; j < 4; ++j) {
                const int vv = v0 + mt * 16 + (lane >> 4) * 4 + j;
                if (vv < VT) {
                    float val = acc[mt][j] + bv;
                    if (vv == VT - 1) val = 0.f;
                    out[((size_t)b * VT + vv) * 3 + lr] = val;
                }
            }
        }
    }
}

extern "C" void kernel_launch(void* const* d_in, const int* in_sizes, int n_in,
                              void* d_out, int out_size, void* d_ws, size_t ws_size,
                              hipStream_t stream) {
    const float* z   = (const float*)d_in[0];
    const float* U0  = (const float*)d_in[1];
    const float* U1  = (const float*)d_in[2];
    const float* U2  = (const float*)d_in[3];
    const int*   S0  = (const int*)d_in[4];
    const int*   S1  = (const int*)d_in[5];
    const int*   S2  = (const int*)d_in[6];
    const float* Wfc = (const float*)d_in[7];
    const float* bfc = (const float*)d_in[8];
    const float* W0  = (const float*)d_in[9];
    const float* b0  = (const float*)d_in[10];
    const float* W1  = (const float*)d_in[11];
    const float* b1  = (const float*)d_in[12];
    const float* W2  = (const float*)d_in[13];
    const float* b2  = (const float*)d_in[14];
    float* out = (float*)d_out;

    char* ws = (char*)d_ws;
    unsigned short* Ub0 = (unsigned short*)(ws + 0);          // [11904][2976]
    unsigned short* Ub1 = (unsigned short*)(ws + 70852608);   // [3072][768]
    unsigned short* Ub2 = (unsigned short*)(ws + 75571200);   // [768][192]
    unsigned short* x3T = (unsigned short*)(ws + 75866112);   // [2048][192]
    unsigned short* x2u = (unsigned short*)(ws + 76652544);   // [16][768][128]
    unsigned short* x2T = (unsigned short*)(ws + 79798272);   // [2048][768]
    unsigned short* x1u = (unsigned short*)(ws + 82944000);   // [16][3072][128]
    unsigned short* x1T = (unsigned short*)(ws + 95526912);   // [1024][3072]
    unsigned short* x0u = (unsigned short*)(ws + 101818368);  // [16][11904][64]
    unsigned short* W0T = (unsigned short*)(ws + 126197760);  // [128][1536]
    unsigned short* W1T = (unsigned short*)(ws + 126590976);  // [64][1792]
    int* S1T = (int*)(ws + 126820352);                        // [14][2949]
    int* S2T = (int*)(ws + 126985504);                        // [12][738]
    int* S0T = (int*)(ws + 127020928);                        // [20][11794]
    unsigned short* W2T = (unsigned short*)(ws + 127964448);  // [16][1288]

    // converters (once per call)
    cvt_ub<<<dim3(12, 11904), 256, 0, stream>>>(U0, Ub0, 11794, 2949, 2976);
    cvt_ub<<<dim3(3, 3072), 256, 0, stream>>>(U1, Ub1, 2949, 738, 768);
    cvt_ub<<<dim3(1, 768), 256, 0, stream>>>(U2, Ub2, 738, 185, 192);
    cvt_wT<<<dim3((128 * 1536 + 255) / 256), 256, 0, stream>>>(W0, W0T, 1536, 128, 128 * 1536);
    cvt_wT<<<dim3((64 * 1792 + 255) / 256), 256, 0, stream>>>(W1, W1T, 1792, 64, 64 * 1792);
    cvt_w2<<<dim3((16 * 1288 + 255) / 256), 256, 0, stream>>>(W2, W2T);
    cvt_sT<<<dim3((14 * 2949 + 255) / 256), 256, 0, stream>>>(S1, S1T, 2949, 14, 14 * 2949);
    cvt_sT<<<dim3((12 * 738 + 255) / 256), 256, 0, stream>>>(S2, S2T, 738, 12, 12 * 738);
    cvt_sT<<<dim3((20 * 11794 + 255) / 256), 256, 0, stream>>>(S0, S0T, 11794, 20, 20 * 11794);
    zero16<<<dim3(192), 256, 0, stream>>>((int4*)x3T, 2048 * 192 * 2 / 16);

    // 1. FC -> x3T
    fc_kernel<<<dim3((185 * 128 + 255) / 256), 256, 0, stream>>>(z, Wfc, bfc, x3T);
    // 2. U2 upsample -> x2u
    ups_mfma<7, 768><<<dim3(96), 256, 0, stream>>>(Ub2, x3T, x2u, 192, 192, 6, 4, 12);
    // 3. conv0 (K=12,128->128,elu) -> x2T : 32-row tiles
    conv_mfma<768><<<dim3(384, 2), 64, 0, stream>>>(x2u, S2T, W0T, b0, x2T, 738, 12, 1536, 48, 128);
    // 4. U1 upsample -> x1u
    ups_mfma<7, 3072><<<dim3(384), 256, 0, stream>>>(Ub1, x2T, x1u, 768, 768, 24, 4, 48);
    // 5. conv1 (K=14,128->64,elu) -> x1T : 32-row tiles
    conv_mfma<3072><<<dim3(1536, 1), 64, 0, stream>>>(x1u, S1T, W1T, b1, x1T, 2949, 14, 1792, 56, 64);
    // 6. U0 upsample -> x0u
    ups_mfma<6, 11904><<<dim3(744), 256, 0, stream>>>(Ub0, x1T, x0u, 2976, 3072, 93, 3, 93);
    // 7. conv2 (K=20, 64->3) as MFMA GEMM -> d_out : 32-row tiles
    out_mfma<<<dim3(16 * 372), 64, 0, stream>>>(x0u, S0T, W2T, b2, out);
}

// Round 9
// 375.398 us; speedup vs baseline: 1.2200x; 1.0613x over previous
//
#include <hip/hip_runtime.h>
#include <cmath>

// Decoder_spirals R8: R7 pipeline with STATIC buffer indices.
// - ups_mfma: 3-buffer, 2-deep prefetch, counted vmcnt(4), hand-unrolled x3
//   (nsteps % 3 == 0 for all levels) -> all LDS addresses compile-time static.
// - conv_mfma / out_mfma: 2-buffer, hand-unrolled x2 (nsteps even), no per-step
//   runtime buf index, no if(more) branches in main loop.
// R7's runtime-rotated buffers cost VALUBusy 37% (rule #20); this removes it.

#define NB 16

typedef __attribute__((ext_vector_type(8))) short bf16x8;
typedef __attribute__((ext_vector_type(4))) float f32x4;

__device__ __forceinline__ unsigned short f2bf(float x) {
    union { float f; unsigned u; } v; v.f = x;
    unsigned r = v.u + 0x7FFFu + ((v.u >> 16) & 1u);
    return (unsigned short)(r >> 16);
}
__device__ __forceinline__ void gload16(const void* src, void* dst) {
    __builtin_amdgcn_global_load_lds(
        (const __attribute__((address_space(1))) unsigned int*)src,
        (__attribute__((address_space(3))) unsigned int*)dst, 16, 0, 0);
}

// ---------------- converters ----------------
__global__ __launch_bounds__(256) void cvt_ub(const float* __restrict__ src,
                                              unsigned short* __restrict__ dst,
                                              int V, int W, int Wp) {
    int k = blockIdx.x * 256 + threadIdx.x;
    int row = blockIdx.y;
    if (k >= Wp) return;
    float v = (row < V && k < W) ? src[(size_t)row * W + k] : 0.f;
    dst[(size_t)row * Wp + k] = f2bf(v);
}
__global__ __launch_bounds__(256) void cvt_wT(const float* __restrict__ w,
                                              unsigned short* __restrict__ wT,
                                              int K, int N, int total) {
    int id = blockIdx.x * 256 + threadIdx.x;
    if (id >= total) return;
    int n = id / K, k = id - n * K;
    wT[id] = f2bf(w[(size_t)k * N + n]);
}
__global__ __launch_bounds__(256) void cvt_w2(const float* __restrict__ w,
                                              unsigned short* __restrict__ wt) {
    int id = blockIdx.x * 256 + threadIdx.x;
    if (id >= 16 * 1288) return;
    int n = id / 1288, k = id - n * 1288;
    float v = (n < 3 && k < 1280) ? w[(size_t)k * 3 + n] : 0.f;
    wt[id] = f2bf(v);
}
__global__ __launch_bounds__(256) void cvt_sT(const int* __restrict__ S,
                                              int* __restrict__ ST,
                                              int V, int K, int total) {
    int id = blockIdx.x * 256 + threadIdx.x;
    if (id >= total) return;
    int k = id / V, v = id - k * V;
    ST[id] = S[(size_t)v * K + k];
}
__global__ __launch_bounds__(256) void zero16(int4* __restrict__ p, int n16) {
    int id = blockIdx.x * 256 + threadIdx.x;
    if (id < n16) p[id] = make_int4(0, 0, 0, 0);
}

// ---------------- FC: z(16,128)@Wfc(128,23680)+bfc -> x3T[b*128+f][192] bf16 ----------------
__global__ __launch_bounds__(256) void fc_kernel(const float* __restrict__ z,
                                                 const float* __restrict__ Wfc,
                                                 const float* __restrict__ bfc,
                                                 unsigned short* __restrict__ x3T) {
    const int N = 185 * 128;
    __shared__ float zs[NB * 128];
    int t = threadIdx.x;
    for (int i = t; i < NB * 128; i += 256) zs[i] = z[i];
    __syncthreads();
    int n = blockIdx.x * 256 + t;
    if (n >= N) return;
    float acc[NB];
#pragma unroll
    for (int b = 0; b < NB; ++b) acc[b] = 0.f;
    for (int k = 0; k < 128; ++k) {
        float w = Wfc[k * N + n];
#pragma unroll
        for (int b = 0; b < NB; ++b) acc[b] = fmaf(zs[b * 128 + k], w, acc[b]);
    }
    float bv = bfc[n];
    int f = n & 127, v = n >> 7;
#pragma unroll
    for (int b = 0; b < NB; ++b)
        x3T[(size_t)(b * 128 + f) * 192 + v] = f2bf(acc[b] + bv);
}

// ------------- Upsample: out[b,v,f] = sum_w U[v,w]*x[b,w,f] -------------
// 3-buffer, 2-deep prefetch, counted vmcnt(4), unrolled x3 (static buf indices).
template<int FSH, int VP>
__global__ __launch_bounds__(256) void ups_mfma(
    const unsigned short* __restrict__ Ub, const unsigned short* __restrict__ xT,
    unsigned short* __restrict__ out,
    int WpA, int WpB, int nsteps, int gxsh, int q) {
    const int F = 1 << FSH;
    __shared__ __align__(16) unsigned short As[3][128 * 32];
    __shared__ __align__(16) unsigned short Bs[3][128 * 32];
    const int t = threadIdx.x;
    const int wv = t >> 6, lane = t & 63;
    const int lr = lane & 15;

    const int flat = blockIdx.x;
    const int wg = (flat & 7) * q + (flat >> 3);
    const int m0 = (wg >> gxsh) * 128;
    const int n0 = (wg & ((1 << gxsh) - 1)) * 128;

    const int srow = lane >> 2;
    const int schunk = (((lane & 3) - ((lane >> 3) & 3)) & 3) * 8;
    const int ii0 = wv * 2, ii1 = wv * 2 + 1;
    const unsigned short* asrc0 = Ub + (size_t)(m0 + ii0 * 16 + srow) * WpA + schunk;
    const unsigned short* asrc1 = Ub + (size_t)(m0 + ii1 * 16 + srow) * WpA + schunk;
    const unsigned short* bsrc0 = xT + (size_t)(n0 + ii0 * 16 + srow) * WpB + schunk;
    const unsigned short* bsrc1 = xT + (size_t)(n0 + ii1 * 16 + srow) * WpB + schunk;

    const int fslot = (((lane >> 4) + (lr >> 1)) & 3) * 8;
    const int wrow = (wv >> 1) * 64;
    const int wcol = (wv & 1) * 64;
    const int u0 = wv * 1024;

    f32x4 acc[4][4];
#pragma unroll
    for (int i = 0; i < 4; ++i)
#pragma unroll
        for (int j = 0; j < 4; ++j) acc[i][j] = {0.f, 0.f, 0.f, 0.f};

#define UPS_STAGE(off_, B_)                                             \
    {                                                                   \
        gload16(asrc0 + (off_), &As[B_][u0]);                           \
        gload16(bsrc0 + (off_), &Bs[B_][u0]);                           \
        gload16(asrc1 + (off_), &As[B_][u0 + 512]);                     \
        gload16(bsrc1 + (off_), &Bs[B_][u0 + 512]);                     \
    }
#define UPS_COMPUTE(B_)                                                 \
    {                                                                   \
        bf16x8 af[4], bg[4];                                            \
        _Pragma("unroll")                                               \
        for (int mt = 0; mt < 4; ++mt)                                  \
            af[mt] = *(const bf16x8*)&As[B_][(wrow + mt * 16 + lr) * 32 + fslot]; \
        _Pragma("unroll")                                               \
        for (int nt = 0; nt < 4; ++nt)                                  \
            bg[nt] = *(const bf16x8*)&Bs[B_][(wcol + nt * 16 + lr) * 32 + fslot]; \
        _Pragma("unroll")                                               \
        for (int mt = 0; mt < 4; ++mt)                                  \
            _Pragma("unroll")                                           \
            for (int nt = 0; nt < 4; ++nt)                              \
                acc[mt][nt] = __builtin_amdgcn_mfma_f32_16x16x32_bf16(  \
                    af[mt], bg[nt], acc[mt][nt], 0, 0, 0);              \
    }
#define UPS_WAIT4 asm volatile("s_waitcnt vmcnt(4)" ::: "memory"); __builtin_amdgcn_s_barrier();
#define UPS_WAIT0 asm volatile("s_waitcnt vmcnt(0)" ::: "memory"); __builtin_amdgcn_s_barrier();

    // prologue: stage steps 0,1
    UPS_STAGE(0, 0);
    UPS_STAGE(32, 1);
    UPS_WAIT4;

    const int m = nsteps / 3;  // nsteps divisible by 3, m >= 2
    for (int it = 0; it < m - 1; ++it) {
        UPS_STAGE(64, 2);  UPS_COMPUTE(0); UPS_WAIT4;
        UPS_STAGE(96, 0);  UPS_COMPUTE(1); UPS_WAIT4;
        UPS_STAGE(128, 1); UPS_COMPUTE(2); UPS_WAIT4;
        asrc0 += 96; asrc1 += 96; bsrc0 += 96; bsrc1 += 96;
    }
    UPS_STAGE(64, 2);
    UPS_COMPUTE(0); UPS_WAIT4;
    UPS_COMPUTE(1); UPS_WAIT0;
    UPS_COMPUTE(2);
#undef UPS_STAGE
#undef UPS_COMPUTE
#undef UPS_WAIT4
#undef UPS_WAIT0

    // epilogue: C row=(lane>>4)*4+j (m), col=lane&15 (n); write bf16 [b][VP][F]
#pragma unroll
    for (int mt = 0; mt < 4; ++mt) {
        const int vb = m0 + wrow + mt * 16 + (lane >> 4) * 4;
#pragma unroll
        for (int nt = 0; nt < 4; ++nt) {
            const int col = n0 + wcol + nt * 16 + lr;
            const int b = col >> FSH, f = col & (F - 1);
            unsigned short* op = out + (size_t)b * VP * F + f;
#pragma unroll
            for (int j = 0; j < 4; ++j)
                op[(size_t)(vb + j) * F] = f2bf(acc[mt][nt][j]);
        }
    }
}

// ------- SpiralConv: gathered-A bf16 GEMM, 32-row 1-wave tiles, unrolled x2 -------
template<int VP>
__global__ __launch_bounds__(64) void conv_mfma(
    const unsigned short* __restrict__ xu, const int* __restrict__ ST,
    const unsigned short* __restrict__ WT, const float* __restrict__ bias,
    unsigned short* __restrict__ outT,
    int VT, int Ksp, int Kdim, int nsteps, int Fout) {
    __shared__ __align__(16) unsigned short As[2][32 * 32];
    __shared__ __align__(16) unsigned short Bs[2][64 * 32];
    const int lane = threadIdx.x;
    const int lr = lane & 15;
    const int m0 = blockIdx.x * 32;
    const int n0 = blockIdx.y * 64;
    const int b = m0 / VP;
    const int v0 = m0 - b * VP;
    const unsigned short* xb = xu + (((size_t)b * VP) << 7);

    const int arow = lane >> 1;
    const int h = lane & 1;
    const int vg = (v0 + arow < VT) ? (v0 + arow) : (VT - 1);
    const int schunk = (((lane & 3) - ((lane >> 3) & 3)) & 3) * 8;
    const int fslot = (((lane >> 4) + (lr >> 1)) & 3) * 8;
    int sw0 = arow * 32 + (((2 * h + 0 + ((lane >> 2) & 3)) & 3) * 8);
    int sw1 = arow * 32 + (((2 * h + 1 + ((lane >> 2) & 3)) & 3) * 8);

    int s_c = 0;
    int idx_c = ST[vg];
    int idx_n = ST[(size_t)VT + vg];

    f32x4 acc[2][4];
#pragma unroll
    for (int i = 0; i < 2; ++i)
#pragma unroll
        for (int j = 0; j < 4; ++j) acc[i][j] = {0.f, 0.f, 0.f, 0.f};

#define CONV_COMPUTE(B_)                                                \
    {                                                                   \
        bf16x8 af[2], bg[4];                                            \
        _Pragma("unroll")                                               \
        for (int mt = 0; mt < 2; ++mt)                                  \
            af[mt] = *(const bf16x8*)&As[B_][(mt * 16 + lr) * 32 + fslot]; \
        _Pragma("unroll")                                               \
        for (int nt = 0; nt < 4; ++nt)                                  \
            bg[nt] = *(const bf16x8*)&Bs[B_][(nt * 16 + lr) * 32 + fslot]; \
        _Pragma("unroll")                                               \
        for (int mt = 0; mt < 2; ++mt)                                  \
            _Pragma("unroll")                                           \
            for (int nt = 0; nt < 4; ++nt)                              \
                acc[mt][nt] = __builtin_amdgcn_mfma_f32_16x16x32_bf16(  \
                    af[mt], bg[nt], acc[mt][nt], 0, 0, 0);              \
    }
#define CONV_BODY(tn_, CUR_, NXT_)                                      \
    {                                                                   \
        const int k0 = (tn_) * 32;                                      \
        const int sn = k0 >> 7;                                         \
        const int idx = (sn != s_c) ? idx_n : idx_c;                    \
        const unsigned short* p = xb + (((size_t)idx) << 7) + (k0 & 127) + h * 16; \
        bf16x8 g0 = *(const bf16x8*)(p);                                \
        bf16x8 g1 = *(const bf16x8*)(p + 8);                            \
        _Pragma("unroll")                                               \
        for (int i = 0; i < 4; ++i) {                                   \
            const int n = n0 + i * 16 + (lane >> 2);                    \
            gload16(WT + (size_t)n * Kdim + k0 + schunk, &Bs[NXT_][i * 512]); \
        }                                                               \
        if (sn != s_c) {                                                \
            idx_c = idx_n; s_c = sn;                                    \
            if (s_c + 1 < Ksp) idx_n = ST[(size_t)(s_c + 1) * VT + vg]; \
        }                                                               \
        CONV_COMPUTE(CUR_);                                             \
        *(bf16x8*)&As[NXT_][sw0] = g0;                                  \
        *(bf16x8*)&As[NXT_][sw1] = g1;                                  \
        __syncthreads();                                                \
    }

    // prologue: step 0 -> buf 0
    {
        const unsigned short* p = xb + (((size_t)idx_c) << 7) + h * 16;
        bf16x8 g0 = *(const bf16x8*)(p);
        bf16x8 g1 = *(const bf16x8*)(p + 8);
#pragma unroll
        for (int i = 0; i < 4; ++i) {
            const int n = n0 + i * 16 + (lane >> 2);
            gload16(WT + (size_t)n * Kdim + schunk, &Bs[0][i * 512]);
        }
        *(bf16x8*)&As[0][sw0] = g0;
        *(bf16x8*)&As[0][sw1] = g1;
    }
    __syncthreads();

    for (int ts = 0; ts + 2 < nsteps; ts += 2) {
        CONV_BODY(ts + 1, 0, 1);
        CONV_BODY(ts + 2, 1, 0);
    }
    CONV_BODY(nsteps - 1, 0, 1);
    CONV_COMPUTE(1);
#undef CONV_BODY
#undef CONV_COMPUTE

#pragma unroll
    for (int nt = 0; nt < 4; ++nt) {
        const int n = n0 + nt * 16 + lr;
        const float bv = bias[n];
        unsigned short* op = outT + (size_t)(b * Fout + n) * VP;
#pragma unroll
        for (int mt = 0; mt < 2; ++mt) {
            const int v = v0 + mt * 16 + (lane >> 4) * 4;
            ushort4 stv;
#pragma unroll
            for (int j = 0; j < 4; ++j) {
                float val = acc[mt][nt][j] + bv;
                val = val > 0.f ? val : expm1f(val);
                if (v + j == VT - 1) val = 0.f;
                ((unsigned short*)&stv)[j] = f2bf(val);
            }
            *(ushort4*)(op + v) = stv;
        }
    }
}

// ------- Final conv as MFMA: 32-row 1-wave tiles, N=16 (3 used), K=1280, unrolled x2 -------
__global__ __launch_bounds__(64) void out_mfma(
    const unsigned short* __restrict__ xu, const int* __restrict__ ST,
    const unsigned short* __restrict__ W2T, const float* __restrict__ b2,
    float* __restrict__ out) {
    const int VT = 11794, VP = 11904, TPB = 372;
    __shared__ __align__(16) unsigned short As[2][32 * 32];
    const int lane = threadIdx.x;
    const int lr = lane & 15;
    const int lko = (lane >> 4) * 8;
    const int bm = blockIdx.x;
    const int b = bm / TPB;
    const int v0 = (bm - b * TPB) * 32;
    const unsigned short* xb = xu + ((size_t)b * VP << 6);

    const int arow = lane >> 1;
    const int h = lane & 1;
    const int v = v0 + arow;
    const int vg = v < VT ? v : VT - 1;
    int sw0 = arow * 32 + (((2 * h + 0 + ((lane >> 2) & 3)) & 3) * 8);
    int sw1 = arow * 32 + (((2 * h + 1 + ((lane >> 2) & 3)) & 3) * 8);
    const int fslot = (((lane >> 4) + (lr >> 1)) & 3) * 8;

    int s_c = 0;
    int idx_c = ST[vg];
    int idx_n = ST[VT + vg];

    f32x4 acc[2];
    acc[0] = {0.f, 0.f, 0.f, 0.f};
    acc[1] = {0.f, 0.f, 0.f, 0.f};

    const unsigned short* wrow = W2T + (size_t)lr * 1288 + lko;
    bf16x8 bg_c = *(const bf16x8*)(wrow);

#define OUT_COMPUTE(B_)                                                 \
    {                                                                   \
        bf16x8 af[2];                                                   \
        _Pragma("unroll")                                               \
        for (int mt = 0; mt < 2; ++mt)                                  \
            af[mt] = *(const bf16x8*)&As[B_][(mt * 16 + lr) * 32 + fslot]; \
        _Pragma("unroll")                                               \
        for (int mt = 0; mt < 2; ++mt)                                  \
            acc[mt] = __builtin_amdgcn_mfma_f32_16x16x32_bf16(af[mt], bg_c, acc[mt], 0, 0, 0); \
    }
#define OUT_BODY(tn_, CUR_, NXT_)                                       \
    {                                                                   \
        const int k0 = (tn_) * 32;                                      \
        const int sn = k0 >> 6;                                         \
        const int idx = (sn != s_c) ? idx_n : idx_c;                    \
        const unsigned short* p = xb + (((size_t)idx) << 6) + (k0 & 63) + h * 16; \
        bf16x8 g0 = *(const bf16x8*)(p);                                \
        bf16x8 g1 = *(const bf16x8*)(p + 8);                            \
        bf16x8 bg_n = *(const bf16x8*)(wrow + k0);                      \
        if (sn != s_c) {                                                \
            idx_c = idx_n; s_c = sn;                                    \
            if (s_c + 1 < 20) idx_n = ST[(size_t)(s_c + 1) * VT + vg];  \
        }                                                               \
        OUT_COMPUTE(CUR_);                                              \
        bg_c = bg_n;                                                    \
        *(bf16x8*)&As[NXT_][sw0] = g0;                                  \
        *(bf16x8*)&As[NXT_][sw1] = g1;                                  \
        __syncthreads();                                                \
    }

    {
        const unsigned short* p = xb + ((size_t)idx_c << 6) + h * 16;
        bf16x8 g0 = *(const bf16x8*)(p);
        bf16x8 g1 = *(const bf16x8*)(p + 8);
        *(bf16x8*)&As[0][sw0] = g0;
        *(bf16x8*)&As[0][sw1] = g1;
    }
    __syncthreads();

    const int nsteps = 40;
    for (int ts = 0; ts + 2 < nsteps; ts += 2) {
        OUT_BODY(ts + 1, 0, 1);
        OUT_BODY(ts + 2, 1, 0);
    }
    OUT_BODY(nsteps - 1, 0, 1);
    OUT_COMPUTE(1);
#undef OUT_BODY
#undef OUT_COMPUTE

    if (lr < 3) {
        const float bv = b2[lr];
#pragma unroll
        for (int mt = 0; mt < 2; ++mt) {
#pragma unroll
            for (int j = 0; j < 4; ++j) {
                const int vv = v0 + mt * 16 + (lane >> 4) * 4 + j;
                if (vv < VT) {
                    float val = acc[mt][j] + bv;
                    if (vv == VT - 1) val = 0.f;
                    out[((size_t)b * VT + vv) * 3 + lr] = val;
                }
            }
        }
    }
}

extern "C" void kernel_launch(void* const* d_in, const int* in_sizes, int n_in,
                              void* d_out, int out_size, void* d_ws, size_t ws_size,
                              hipStream_t stream) {
    const float* z   = (const float*)d_in[0];
    const float* U0  = (const float*)d_in[1];
    const float* U1  = (const float*)d_in[2];
    const float* U2  = (const float*)d_in[3];
    const int*   S0  = (const int*)d_in[4];
    const int*   S1  = (const int*)d_in[5];
    const int*   S2  = (const int*)d_in[6];
    const float* Wfc = (const float*)d_in[7];
    const float* bfc = (const float*)d_in[8];
    const float* W0  = (const float*)d_in[9];
    const float* b0  = (const float*)d_in[10];
    const float* W1  = (const float*)d_in[11];
    const float* b1  = (const float*)d_in[12];
    const float* W2  = (const float*)d_in[13];
    const float* b2  = (const float*)d_in[14];
    float* out = (float*)d_out;

    char* ws = (char*)d_ws;
    unsigned short* Ub0 = (unsigned short*)(ws + 0);          // [11904][2976]
    unsigned short* Ub1 = (unsigned short*)(ws + 70852608);   // [3072][768]
    unsigned short* Ub2 = (unsigned short*)(ws + 75571200);   // [768][192]
    unsigned short* x3T = (unsigned short*)(ws + 75866112);   // [2048][192]
    unsigned short* x2u = (unsigned short*)(ws + 76652544);   // [16][768][128]
    unsigned short* x2T = (unsigned short*)(ws + 79798272);   // [2048][768]
    unsigned short* x1u = (unsigned short*)(ws + 82944000);   // [16][3072][128]
    unsigned short* x1T = (unsigned short*)(ws + 95526912);   // [1024][3072]
    unsigned short* x0u = (unsigned short*)(ws + 101818368);  // [16][11904][64]
    unsigned short* W0T = (unsigned short*)(ws + 126197760);  // [128][1536]
    unsigned short* W1T = (unsigned short*)(ws + 126590976);  // [64][1792]
    int* S1T = (int*)(ws + 126820352);                        // [14][2949]
    int* S2T = (int*)(ws + 126985504);                        // [12][738]
    int* S0T = (int*)(ws + 127020928);                        // [20][11794]
    unsigned short* W2T = (unsigned short*)(ws + 127964448);  // [16][1288]

    // converters (once per call)
    cvt_ub<<<dim3(12, 11904), 256, 0, stream>>>(U0, Ub0, 11794, 2949, 2976);
    cvt_ub<<<dim3(3, 3072), 256, 0, stream>>>(U1, Ub1, 2949, 738, 768);
    cvt_ub<<<dim3(1, 768), 256, 0, stream>>>(U2, Ub2, 738, 185, 192);
    cvt_wT<<<dim3((128 * 1536 + 255) / 256), 256, 0, stream>>>(W0, W0T, 1536, 128, 128 * 1536);
    cvt_wT<<<dim3((64 * 1792 + 255) / 256), 256, 0, stream>>>(W1, W1T, 1792, 64, 64 * 1792);
    cvt_w2<<<dim3((16 * 1288 + 255) / 256), 256, 0, stream>>>(W2, W2T);
    cvt_sT<<<dim3((14 * 2949 + 255) / 256), 256, 0, stream>>>(S1, S1T, 2949, 14, 14 * 2949);
    cvt_sT<<<dim3((12 * 738 + 255) / 256), 256, 0, stream>>>(S2, S2T, 738, 12, 12 * 738);
    cvt_sT<<<dim3((20 * 11794 + 255) / 256), 256, 0, stream>>>(S0, S0T, 11794, 20, 20 * 11794);
    zero16<<<dim3(192), 256, 0, stream>>>((int4*)x3T, 2048 * 192 * 2 / 16);

    // 1. FC -> x3T
    fc_kernel<<<dim3((185 * 128 + 255) / 256), 256, 0, stream>>>(z, Wfc, bfc, x3T);
    // 2. U2 upsample -> x2u : nsteps=6
    ups_mfma<7, 768><<<dim3(96), 256, 0, stream>>>(Ub2, x3T, x2u, 192, 192, 6, 4, 12);
    // 3. conv0 (K=12,128->128,elu) -> x2T : 32-row tiles, nsteps=48
    conv_mfma<768><<<dim3(384, 2), 64, 0, stream>>>(x2u, S2T, W0T, b0, x2T, 738, 12, 1536, 48, 128);
    // 4. U1 upsample -> x1u : nsteps=24
    ups_mfma<7, 3072><<<dim3(384), 256, 0, stream>>>(Ub1, x2T, x1u, 768, 768, 24, 4, 48);
    // 5. conv1 (K=14,128->64,elu) -> x1T : 32-row tiles, nsteps=56
    conv_mfma<3072><<<dim3(1536, 1), 64, 0, stream>>>(x1u, S1T, W1T, b1, x1T, 2949, 14, 1792, 56, 64);
    // 6. U0 upsample -> x0u : nsteps=93
    ups_mfma<6, 11904><<<dim3(744), 256, 0, stream>>>(Ub0, x1T, x0u, 2976, 3072, 93, 3, 93);
    // 7. conv2 (K=20, 64->3) as MFMA GEMM -> d_out : 32-row tiles, nsteps=40
    out_mfma<<<dim3(16 * 372), 64, 0, stream>>>(x0u, S0T, W2T, b2, out);
}